// Round 14
// baseline (108.767 us; speedup 1.0000x reference)
//
#include <hip/hip_runtime.h>
#include <cstdint>
#include <cstddef>

typedef unsigned short u16;
typedef __bf16 bf16x8 __attribute__((ext_vector_type(8)));
typedef float f32x4 __attribute__((ext_vector_type(4)));
typedef unsigned int u32x4 __attribute__((ext_vector_type(4)));

#define DEVI __device__ __forceinline__

constexpr int SEQ = 2048, NH = 16, HD = 64, EMB = 1024, N3 = 3072, MROWS = 4096;

// round-to-nearest-even f32 -> bf16
DEVI u16 f2bf(float f) {
    union { float f; unsigned u; } x; x.f = f;
    unsigned r = (x.u + 0x7fffu + ((x.u >> 16) & 1u)) >> 16;
    return (u16)r;
}

DEVI f32x4 mfma16(bf16x8 a, bf16x8 b, f32x4 c) {
    return __builtin_amdgcn_mfma_f32_16x16x32_bf16(a, b, c, 0, 0, 0);
}

// raw v_exp_f32 (2^x): 1 instr, vs exp2f's OCML subnormal-edge path (~5-6 instr)
DEVI float exp2_raw(float x) {
    float r;
    asm("v_exp_f32 %0, %1" : "=v"(r) : "v"(x));
    return r;
}

#define GLDS16(g, l)                                                          \
    __builtin_amdgcn_global_load_lds(                                         \
        (__attribute__((address_space(1))) void*)(g),                         \
        (__attribute__((address_space(3))) void*)(l), 16, 0, 0)

// ---------------- fused prep kernel ----------------
// blocks [0,4096): x f32->bf16 ; [4096,4864): W_qkv transpose ; [4864,5120): W_out transpose ;
// [5120,5376): rope cos/sin table
__global__ __launch_bounds__(256) void prep_k(const float* __restrict__ x,
                                              const float* __restrict__ wqk,
                                              const float* __restrict__ wo,
                                              u16* __restrict__ xb, u16* __restrict__ wqkvT,
                                              u16* __restrict__ woutT, float2* __restrict__ tab) {
    __shared__ float tile[64][65];
    int bid = blockIdx.x, tid = threadIdx.x;
    if (bid < 4096) {
        int i = bid * 256 + tid;
        float4 v = ((const float4*)x)[i];
        ushort4 o;
        o.x = f2bf(v.x); o.y = f2bf(v.y); o.z = f2bf(v.z); o.w = f2bf(v.w);
        ((ushort4*)xb)[i] = o;
    } else if (bid < 5120) {
        const float* in; u16* out; int N, bx, by;
        if (bid < 4864) { in = wqk; out = wqkvT; N = 3072; int bb = bid - 4096; bx = bb % 48; by = bb / 48; }
        else            { in = wo;  out = woutT; N = 1024; int bb = bid - 4864; bx = bb % 16; by = bb / 16; }
        const int K = 1024;
        int k0 = by * 64, n0 = bx * 64;
        for (int i = 0; i < 16; i++) {
            int idx = i * 256 + tid;
            int r = idx >> 6, c = idx & 63;
            tile[r][c] = in[(size_t)(k0 + r) * N + n0 + c];
        }
        __syncthreads();
        for (int i = 0; i < 16; i++) {
            int idx = i * 256 + tid;
            int n = idx >> 6, k = idx & 63;
            out[(size_t)(n0 + n) * K + k0 + k] = f2bf(tile[k][n]);
        }
    } else {
        int idx = (bid - 5120) * 256 + tid;  // SEQ*32
        int t = idx >> 5, i = idx & 31;
        double ang = (double)t * pow(10000.0, -(double)i / 32.0);
        tab[idx] = make_float2((float)cos(ang), (float)sin(ang));
    }
}

// ---------------- GEMM: 128x128xBK32, 4 waves, dbuf gload_lds, 4 blocks/CU ----------------
// BK=32 halves LDS (34KB incl. epilogue overlay) -> 4 blocks/CU so the whole 768-block grid
// is co-resident (was 2/CU, 1.5 sequential rounds). Same 1-barrier/iter dbuf pattern.
// Swizzle (4 chunks/row): source chunk c ^ ((row>>1)&3); read chunk lg ^ ((l15>>1)&3)
// -> uniform 8 lanes per 16B slot (wave-b128 floor; 2-way within slot is free).
template <int EPI>
__global__ __launch_bounds__(256, 4) void gemm128_k(const u16* __restrict__ A, const u16* __restrict__ Bt,
                                                    int Kd, int Ncols,
                                                    u16* __restrict__ q_out, u16* __restrict__ k_out,
                                                    u16* __restrict__ v_out,
                                                    const float2* __restrict__ tab,
                                                    float* __restrict__ Cout) {
    __shared__ __align__(16) u16 smem[17408];  // A0|A1|B0|B1 (4096 u16 each); epilogue [128][136]
    u16* As0 = smem;
    u16* As1 = smem + 4096;
    u16* Bs0 = smem + 8192;
    u16* Bs1 = smem + 12288;
    int tid = threadIdx.x, lane = tid & 63, wv = tid >> 6;
    int wr = wv >> 1, wc = wv & 1;
    int l15 = lane & 15, lg = lane >> 4;
    int fr = (l15 >> 1) & 3;  // read-side swizzle

    // T1: bijective XCD swizzle (nwg % 8 == 0 for both GEMMs)
    int nwg = gridDim.x * gridDim.y;
    int bid = blockIdx.y * gridDim.x + blockIdx.x;
    int swzb = (bid & 7) * (nwg >> 3) + (bid >> 3);
    int bx = swzb % gridDim.x, by = swzb / gridDim.x;
    int brow = by * 128, bcol = bx * 128;

    f32x4 acc[4][4];
    for (int i = 0; i < 4; i++)
        for (int j = 0; j < 4; j++) acc[i][j] = (f32x4){0.f, 0.f, 0.f, 0.f};

    // staging: chunk c in [0,512): row c>>2, slot c&3; source chunk = (c&3) ^ ((row>>1)&3)
    const u16* aptr[2];
    const u16* bptr[2];
#pragma unroll
    for (int i = 0; i < 2; i++) {
        int cidx = i * 256 + tid;
        int rrow = cidx >> 2, cc = cidx & 3;
        int sw = (cc ^ ((rrow >> 1) & 3)) * 8;
        aptr[i] = A + (size_t)(brow + rrow) * Kd + sw;
        bptr[i] = Bt + (size_t)(bcol + rrow) * Kd + sw;
    }

    auto stageG = [&](u16* Ad, u16* Bd) {
#pragma unroll
        for (int i = 0; i < 2; i++) {
            GLDS16(aptr[i], Ad + (i * 256 + tid) * 8);
            GLDS16(bptr[i], Bd + (i * 256 + tid) * 8);
            aptr[i] += 32;
            bptr[i] += 32;
        }
    };

    auto computeT = [&](const u16* Ar, const u16* Br) {
        bf16x8 af[4], bf[4];
#pragma unroll
        for (int mi = 0; mi < 4; mi++)
            af[mi] = *(const bf16x8*)&Ar[(wr * 64 + mi * 16 + l15) * 32 + (lg ^ fr) * 8];
#pragma unroll
        for (int ni = 0; ni < 4; ni++)
            bf[ni] = *(const bf16x8*)&Br[(wc * 64 + ni * 16 + l15) * 32 + (lg ^ fr) * 8];
#pragma unroll
        for (int mi = 0; mi < 4; mi++)
#pragma unroll
            for (int ni = 0; ni < 4; ni++)
                acc[mi][ni] = mfma16(af[mi], bf[ni], acc[mi][ni]);
    };

    int nIter = Kd >> 5;  // 32 (even)
    stageG(As0, Bs0);     // tile 0
    for (int it = 0; it < nIter; it += 2) {
        __syncthreads();                              // drains tile-it loads (buf0)
        if (it + 1 < nIter) stageG(As1, Bs1);         // tile it+1
        computeT(As0, Bs0);
        __syncthreads();                              // drains tile-(it+1) loads (buf1)
        if (it + 2 < nIter) stageG(As0, Bs0);         // tile it+2
        computeT(As1, Bs1);
    }

    if constexpr (EPI == 0) {
        int c = bcol >> 10;  // 0=q 1=k 2=v (128-wide tile never crosses a region)
        int bb = brow >> 11, sbase = brow & 2047;
        int hbase = (bcol & 1023) >> 6;  // head of col 0 of this tile (tile spans 2 heads)
        if (c == 2) {
            // v^T [b][h][d][s]: r-quad = 4 consecutive s at fixed d -> packed 8B stores
            for (int mi = 0; mi < 4; mi++)
                for (int ni = 0; ni < 4; ni++) {
                    int col = wc * 64 + ni * 16 + l15;
                    int d = col & 63, h2 = col >> 6;
                    int s0 = sbase + wr * 64 + mi * 16 + lg * 4;
                    ushort4 pw;
                    pw.x = f2bf(acc[mi][ni][0]);
                    pw.y = f2bf(acc[mi][ni][1]);
                    pw.z = f2bf(acc[mi][ni][2]);
                    pw.w = f2bf(acc[mi][ni][3]);
                    *(ushort4*)&v_out[((size_t)(bb * NH + hbase + h2) * HD + d) * SEQ + s0] = pw;
                }
        } else {
            u16* dst = (c == 0) ? q_out : k_out;
            // q gets softmax scale 1/8 plus log2(e) fold so attn can use raw v_exp_f32
            float sc = (c == 0) ? 0.125f * 1.4426950408889634f : 1.0f;
            u16* ep = smem;  // [128 rows][136] u16, chunk-XOR swizzled (overlays As/Bs)
            __syncthreads();  // waves may still be reading fragments from smem
            for (int mi = 0; mi < 4; mi++)
                for (int ni = 0; ni < 4; ni++) {
                    int col = wc * 64 + ni * 16 + l15;
                    int dg = col & 63;
                    for (int r = 0; r < 4; r++) {
                        int rowl = wr * 64 + mi * 16 + lg * 4 + r;
                        int s = sbase + rowl;
                        float val = acc[mi][ni][r];
                        float part = __shfl_xor(val, 1);  // partner dim d^1 lives in lane^1
                        float2 cs = tab[(s << 5) | (dg >> 1)];
                        float o = (dg & 1) ? (val * cs.x + part * cs.y)
                                           : (val * cs.x - part * cs.y);
                        ep[rowl * 136 + (col ^ ((rowl & 7) << 3))] = f2bf(o * sc);
                    }
                }
            __syncthreads();
            // readout: 8 passes x (8 lanes per 128B s-row) -> 1KB contiguous per wave-instr
#pragma unroll
            for (int p = 0; p < 8; p++) {
                int unit = p * 32 + (tid >> 3);          // [0,256): h2*128 + s_row
                int h2 = unit >> 7, s_r = unit & 127, j = tid & 7;
                int cj = (h2 * 8 + j) ^ (s_r & 7);       // un-swizzle chunk
                uint4 w = *(const uint4*)&ep[s_r * 136 + cj * 8];
                *(uint4*)&dst[(((size_t)(bb * NH + hbase + h2) * SEQ + sbase + s_r) << 6) +
                              j * 8] = w;
            }
        }
    } else {
        for (int mi = 0; mi < 4; mi++)
            for (int ni = 0; ni < 4; ni++) {
                int col = bcol + wc * 64 + ni * 16 + l15;
                for (int r = 0; r < 4; r++) {
                    int row = brow + wr * 64 + mi * 16 + lg * 4 + r;
                    Cout[(size_t)row * Ncols + col] = acc[mi][ni][r];
                }
            }
    }
}

// ---------------- flash attention v8: P stays in registers (no Pl LDS) ----------------
// kf[nt] loaded from PERMUTED K row sigma_nt(l15) = (nt>>1)*32 + (l15>>2)*8 + (nt&1)*4 + (l15&3)
// so QK output slots give lane (l15,lg) exactly keys kt*32+lg*8+{0..7} = PV A-operand layout.
// pa = cvt_pk pairs directly; V natural. LDS swizzle f(row) = (row&3)|((row>>1)&4) both-sides.
__global__ __launch_bounds__(256, 2) void attn8_k(const u16* __restrict__ Qb,
                                                  const u16* __restrict__ Kb,
                                                  const u16* __restrict__ Vtg,
                                                  u16* __restrict__ Ob) {
    __shared__ __align__(16) u16 Ks[2][64 * 64];
    __shared__ __align__(16) u16 Vs[2][64 * 64];
    int tid = threadIdx.x, lane = tid & 63, wv = tid >> 6;
    int l15 = lane & 15, lg = lane >> 4;
    int fk = (l15 & 3) | (((l15 >> 2) & 1) << 2);  // f(sigma-row) for K reads
    int fv = (l15 & 3) | (((l15 >> 3) & 1) << 2);  // f(natural row) for V reads
    int bh = blockIdx.y, b = bh >> 4, h = bh & 15;
    int qbase = blockIdx.x * 128;
    const size_t base = (size_t)bh * SEQ * HD;  // same product for [s][d] and [d][s]

    int c0 = tid, c1 = 256 + tid;
    int r0 = c0 >> 3, s0 = ((c0 & 7) ^ ((r0 & 3) | ((r0 >> 1) & 4))) * 8;
    int r1 = c1 >> 3, s1 = ((c1 & 7) ^ ((r1 & 3) | ((r1 >> 1) & 4))) * 8;
    const u16* kp0 = Kb + base + r0 * HD + s0;
    const u16* kp1 = Kb + base + r1 * HD + s1;
    const u16* vp0 = Vtg + base + (size_t)r0 * SEQ + s0;
    const u16* vp1 = Vtg + base + (size_t)r1 * SEQ + s1;

    bf16x8 qf[2][2];
#pragma unroll
    for (int u = 0; u < 2; u++)
#pragma unroll
        for (int kt = 0; kt < 2; kt++)
            qf[u][kt] = *(const bf16x8*)&Qb[base + (size_t)(qbase + wv * 32 + u * 16 + l15) * HD +
                                            kt * 32 + lg * 8];

    f32x4 oacc[2][4];
    float Lp[2] = {0.f, 0.f};
#pragma unroll
    for (int u = 0; u < 2; u++)
#pragma unroll
        for (int nt = 0; nt < 4; nt++) oacc[u][nt] = (f32x4){0.f, 0.f, 0.f, 0.f};

    auto stage = [&](int buf) {
        GLDS16(kp0, &Ks[buf][c0 * 8]);
        GLDS16(kp1, &Ks[buf][c1 * 8]);
        GLDS16(vp0, &Vs[buf][c0 * 8]);
        GLDS16(vp1, &Vs[buf][c1 * 8]);
        kp0 += 64 * HD; kp1 += 64 * HD;
        vp0 += 64; vp1 += 64;
    };

    stage(0);

    for (int it = 0; it < 32; ++it) {
        int buf = it & 1;
        __syncthreads();  // vmcnt(0)+barrier: buf's loads ready; prev iter's reads of buf^1 done
        if (it < 31) stage(buf ^ 1);

        // K fragments from permuted rows sigma_nt(l15); V fragments natural
        bf16x8 kf[4][2], vf[4][2];
#pragma unroll
        for (int nt = 0; nt < 4; nt++) {
            int rk = ((nt >> 1) << 5) + ((l15 >> 2) << 3) + ((nt & 1) << 2) + (l15 & 3);
#pragma unroll
            for (int kt = 0; kt < 2; kt++) {
                kf[nt][kt] = *(const bf16x8*)&Ks[buf][rk * 64 + (((kt * 4 + lg) ^ fk)) * 8];
                vf[nt][kt] = *(const bf16x8*)&Vs[buf][(nt * 16 + l15) * 64 +
                                                     (((kt * 4 + lg) ^ fv)) * 8];
            }
        }

        unsigned pk[2][4][2];
#pragma unroll
        for (int u = 0; u < 2; u++) {
            f32x4 sa[4];
            __builtin_amdgcn_s_setprio(1);
#pragma unroll
            for (int nt = 0; nt < 4; nt++) {
                f32x4 z = (f32x4){0.f, 0.f, 0.f, 0.f};
#pragma unroll
                for (int kt = 0; kt < 2; kt++) z = mfma16(kf[nt][kt], qf[u][kt], z);
                sa[nt] = z;
            }
            __builtin_amdgcn_s_setprio(0);
            // lane (l15,lg): sa[nt][r] = P[key=(nt>>1)*32+lg*8+(nt&1)*4+r][qrow=l15]
            float ls = 0.f;
#pragma unroll
            for (int nt = 0; nt < 4; nt++) {
                float e0 = exp2_raw(sa[nt][0]), e1 = exp2_raw(sa[nt][1]);
                float e2 = exp2_raw(sa[nt][2]), e3 = exp2_raw(sa[nt][3]);
                ls += (e0 + e1) + (e2 + e3);
                asm("v_cvt_pk_bf16_f32 %0, %1, %2" : "=v"(pk[u][nt][0]) : "v"(e0), "v"(e1));
                asm("v_cvt_pk_bf16_f32 %0, %1, %2" : "=v"(pk[u][nt][1]) : "v"(e2), "v"(e3));
            }
            Lp[u] += ls;
        }

        // PV: A-operand = P directly from registers (keys kt*32+lg*8+{0..7} per lane)
        bf16x8 pa[2][2];
#pragma unroll
        for (int u = 0; u < 2; u++)
#pragma unroll
            for (int kt = 0; kt < 2; kt++) {
                u32x4 t = {pk[u][2 * kt][0], pk[u][2 * kt][1], pk[u][2 * kt + 1][0],
                           pk[u][2 * kt + 1][1]};
                pa[u][kt] = __builtin_bit_cast(bf16x8, t);
            }
        __builtin_amdgcn_s_setprio(1);
#pragma unroll
        for (int kt = 0; kt < 2; kt++)
#pragma unroll
            for (int nt = 0; nt < 4; nt++)
#pragma unroll
                for (int u = 0; u < 2; u++)
                    oacc[u][nt] = mfma16(pa[u][kt], vf[nt][kt], oacc[u][nt]);
        __builtin_amdgcn_s_setprio(0);
    }

    float linv[2][4];
#pragma unroll
    for (int u = 0; u < 2; u++) {
        float L = Lp[u];
        L += __shfl_xor(L, 16);
        L += __shfl_xor(L, 32);
#pragma unroll
        for (int r = 0; r < 4; r++) linv[u][r] = 1.0f / __shfl(L, lg * 4 + r);
    }
#pragma unroll
    for (int u = 0; u < 2; u++)
#pragma unroll
        for (int nt = 0; nt < 4; nt++)
#pragma unroll
            for (int r = 0; r < 4; r++) {
                int row = qbase + wv * 32 + u * 16 + lg * 4 + r;
                Ob[(size_t)(b * SEQ + row) * EMB + h * HD + nt * 16 + l15] =
                    f2bf(oacc[u][nt][r] * linv[u][r]);
            }
}

// ---------------- launch ----------------

extern "C" void kernel_launch(void* const* d_in, const int* in_sizes, int n_in,
                              void* d_out, int out_size, void* d_ws, size_t ws_size,
                              hipStream_t stream) {
    const float* x = (const float*)d_in[0];
    const float* wqk = (const float*)d_in[1];
    const float* wo = (const float*)d_in[2];
    float* out = (float*)d_out;
    char* ws = (char*)d_ws;

    u16* xb = (u16*)(ws + 0);                  //  8,388,608  x as bf16 [4096][1024]
    u16* wqkvT = (u16*)(ws + 8388608);         //  6,291,456  W_qkv^T bf16 [3072][1024]
    u16* woutT = (u16*)(ws + 14680064);        //  2,097,152  W_out^T bf16 [1024][1024]
    u16* qb = (u16*)(ws + 16777216);           //  8,388,608  q roped+scaled [b][h][s][d]
    u16* kb = (u16*)(ws + 25165824);           //  8,388,608  k roped [b][h][s][d]
    u16* vb = (u16*)(ws + 33554432);           //  8,388,608  v transposed [b][h][d][s]
    u16* ao = (u16*)(ws + 41943040);           //  8,388,608  attn out [b][s][h*64+d]
    float2* tab = (float2*)(ws + 50331648);    //    524,288  cos/sin [2048][32]

    prep_k<<<5376, 256, 0, stream>>>(x, wqk, wo, xb, wqkvT, woutT, tab);
    gemm128_k<0><<<dim3(N3 / 128, MROWS / 128), 256, 0, stream>>>(xb, wqkvT, EMB, N3, qb, kb, vb,
                                                                  tab, nullptr);
    attn8_k<<<dim3(SEQ / 128, 2 * NH), 256, 0, stream>>>(qb, kb, vb, ao);
    gemm128_k<1><<<dim3(EMB / 128, MROWS / 128), 256, 0, stream>>>(ao, woutT, EMB, EMB, nullptr,
                                                                   nullptr, nullptr, nullptr, out);
}

// Round 15
// 104.597 us; speedup vs baseline: 1.0399x; 1.0399x over previous
//
#include <hip/hip_runtime.h>
#include <cstdint>
#include <cstddef>

typedef unsigned short u16;
typedef __bf16 bf16x8 __attribute__((ext_vector_type(8)));
typedef float f32x4 __attribute__((ext_vector_type(4)));
typedef unsigned int u32x4 __attribute__((ext_vector_type(4)));

#define DEVI __device__ __forceinline__

constexpr int SEQ = 2048, NH = 16, HD = 64, EMB = 1024, N3 = 3072, MROWS = 4096;

// round-to-nearest-even f32 -> bf16
DEVI u16 f2bf(float f) {
    union { float f; unsigned u; } x; x.f = f;
    unsigned r = (x.u + 0x7fffu + ((x.u >> 16) & 1u)) >> 16;
    return (u16)r;
}

DEVI f32x4 mfma16(bf16x8 a, bf16x8 b, f32x4 c) {
    return __builtin_amdgcn_mfma_f32_16x16x32_bf16(a, b, c, 0, 0, 0);
}

// raw v_exp_f32 (2^x)
DEVI float exp2_raw(float x) {
    float r;
    asm("v_exp_f32 %0, %1" : "=v"(r) : "v"(x));
    return r;
}

#define GLDS16(g, l)                                                          \
    __builtin_amdgcn_global_load_lds(                                         \
        (__attribute__((address_space(1))) void*)(g),                         \
        (__attribute__((address_space(3))) void*)(l), 16, 0, 0)

// counted waits + raw barrier (T4): tile-ahead loads stay in flight across the barrier.
#define GWAIT4 asm volatile("s_waitcnt vmcnt(4)" ::: "memory")
#define GWAIT0 asm volatile("s_waitcnt vmcnt(0)" ::: "memory")
#define RBAR                                                                  \
    do {                                                                      \
        __builtin_amdgcn_sched_barrier(0);                                    \
        __builtin_amdgcn_s_barrier();                                         \
        __builtin_amdgcn_sched_barrier(0);                                    \
    } while (0)

// ---------------- fused prep kernel ----------------
// blocks [0,4096): x f32->bf16 ; [4096,4864): W_qkv transpose ; [4864,5120): W_out transpose ;
// [5120,5376): rope cos/sin table
__global__ __launch_bounds__(256) void prep_k(const float* __restrict__ x,
                                              const float* __restrict__ wqk,
                                              const float* __restrict__ wo,
                                              u16* __restrict__ xb, u16* __restrict__ wqkvT,
                                              u16* __restrict__ woutT, float2* __restrict__ tab) {
    __shared__ float tile[64][65];
    int bid = blockIdx.x, tid = threadIdx.x;
    if (bid < 4096) {
        int i = bid * 256 + tid;
        float4 v = ((const float4*)x)[i];
        ushort4 o;
        o.x = f2bf(v.x); o.y = f2bf(v.y); o.z = f2bf(v.z); o.w = f2bf(v.w);
        ((ushort4*)xb)[i] = o;
    } else if (bid < 5120) {
        const float* in; u16* out; int N, bx, by;
        if (bid < 4864) { in = wqk; out = wqkvT; N = 3072; int bb = bid - 4096; bx = bb % 48; by = bb / 48; }
        else            { in = wo;  out = woutT; N = 1024; int bb = bid - 4864; bx = bb % 16; by = bb / 16; }
        const int K = 1024;
        int k0 = by * 64, n0 = bx * 64;
        for (int i = 0; i < 16; i++) {
            int idx = i * 256 + tid;
            int r = idx >> 6, c = idx & 63;
            tile[r][c] = in[(size_t)(k0 + r) * N + n0 + c];
        }
        __syncthreads();
        for (int i = 0; i < 16; i++) {
            int idx = i * 256 + tid;
            int n = idx >> 6, k = idx & 63;
            out[(size_t)(n0 + n) * K + k0 + k] = f2bf(tile[k][n]);
        }
    } else {
        int idx = (bid - 5120) * 256 + tid;  // SEQ*32
        int t = idx >> 5, i = idx & 31;
        double ang = (double)t * pow(10000.0, -(double)i / 32.0);
        tab[idx] = make_float2((float)cos(ang), (float)sin(ang));
    }
}

// ---------------- GEMM: 128x128xBK32, TRIPLE-buffered, counted vmcnt (T4) ----------------
// Loop (K=1024, 32 tiles): prologue stages tiles 0,1; iter t does
//   vmcnt(4) [oldest tile done, next tile's 4 DMAs stay in flight] ; raw s_barrier ;
//   stage(t+2) ; compute(buf t%3).  Never vmcnt(0) until the 2-iter tail.
// Buf bases compile-time via 3-unrolled rounds (10x) + tail.
template <int EPI>
__global__ __launch_bounds__(256, 3) void gemm128_k(const u16* __restrict__ A, const u16* __restrict__ Bt,
                                                    int Kd, int Ncols,
                                                    u16* __restrict__ q_out, u16* __restrict__ k_out,
                                                    u16* __restrict__ v_out,
                                                    const float2* __restrict__ tab,
                                                    float* __restrict__ Cout) {
    __shared__ __align__(16) u16 smem[24576];  // 3 bufs x (A 4096 | B 4096) u16; epi overlay 17408
    int tid = threadIdx.x, lane = tid & 63, wv = tid >> 6;
    int wr = wv >> 1, wc = wv & 1;
    int l15 = lane & 15, lg = lane >> 4;
    int fr = (l15 >> 1) & 3;  // read-side swizzle

    // T1: bijective XCD swizzle (nwg % 8 == 0 for both GEMMs)
    int nwg = gridDim.x * gridDim.y;
    int bid = blockIdx.y * gridDim.x + blockIdx.x;
    int swzb = (bid & 7) * (nwg >> 3) + (bid >> 3);
    int bx = swzb % gridDim.x, by = swzb / gridDim.x;
    int brow = by * 128, bcol = bx * 128;

    f32x4 acc[4][4];
    for (int i = 0; i < 4; i++)
        for (int j = 0; j < 4; j++) acc[i][j] = (f32x4){0.f, 0.f, 0.f, 0.f};

    // staging: chunk c in [0,512): row c>>2, slot c&3; source chunk = (c&3) ^ ((row>>1)&3)
    const u16* aptr[2];
    const u16* bptr[2];
#pragma unroll
    for (int i = 0; i < 2; i++) {
        int cidx = i * 256 + tid;
        int rrow = cidx >> 2, cc = cidx & 3;
        int sw = (cc ^ ((rrow >> 1) & 3)) * 8;
        aptr[i] = A + (size_t)(brow + rrow) * Kd + sw;
        bptr[i] = Bt + (size_t)(bcol + rrow) * Kd + sw;
    }

    auto stageG = [&](u16* base) {  // base: A at base, B at base+4096 (4 DMA/thread)
#pragma unroll
        for (int i = 0; i < 2; i++) {
            GLDS16(aptr[i], base + (i * 256 + tid) * 8);
            GLDS16(bptr[i], base + 4096 + (i * 256 + tid) * 8);
            aptr[i] += 32;
            bptr[i] += 32;
        }
    };

    auto computeT = [&](const u16* base) {
        const u16* Ar = base;
        const u16* Br = base + 4096;
        bf16x8 af[4], bf[4];
#pragma unroll
        for (int mi = 0; mi < 4; mi++)
            af[mi] = *(const bf16x8*)&Ar[(wr * 64 + mi * 16 + l15) * 32 + (lg ^ fr) * 8];
#pragma unroll
        for (int ni = 0; ni < 4; ni++)
            bf[ni] = *(const bf16x8*)&Br[(wc * 64 + ni * 16 + l15) * 32 + (lg ^ fr) * 8];
#pragma unroll
        for (int mi = 0; mi < 4; mi++)
#pragma unroll
            for (int ni = 0; ni < 4; ni++)
                acc[mi][ni] = mfma16(af[mi], bf[ni], acc[mi][ni]);
    };

    u16* b0 = smem;
    u16* b1 = smem + 8192;
    u16* b2 = smem + 16384;

    // 32 tiles (Kd = 1024 for both GEMMs): prologue 2, 10 rounds of 3, tail 2
    stageG(b0);
    stageG(b1);
    for (int r = 0; r < 10; ++r) {
        GWAIT4; RBAR; stageG(b2); computeT(b0);
        GWAIT4; RBAR; stageG(b0); computeT(b1);
        GWAIT4; RBAR; stageG(b1); computeT(b2);
    }
    GWAIT4; RBAR; computeT(b0);  // tile 30 (tile 31's loads still in flight)
    GWAIT0; RBAR; computeT(b1);  // tile 31

    if constexpr (EPI == 0) {
        int c = bcol >> 10;  // 0=q 1=k 2=v (128-wide tile never crosses a region)
        int bb = brow >> 11, sbase = brow & 2047;
        int hbase = (bcol & 1023) >> 6;  // head of col 0 of this tile (tile spans 2 heads)
        if (c == 2) {
            // v^T [b][h][d][s]: r-quad = 4 consecutive s at fixed d -> packed 8B stores
            for (int mi = 0; mi < 4; mi++)
                for (int ni = 0; ni < 4; ni++) {
                    int col = wc * 64 + ni * 16 + l15;
                    int d = col & 63, h2 = col >> 6;
                    int s0 = sbase + wr * 64 + mi * 16 + lg * 4;
                    ushort4 pw;
                    pw.x = f2bf(acc[mi][ni][0]);
                    pw.y = f2bf(acc[mi][ni][1]);
                    pw.z = f2bf(acc[mi][ni][2]);
                    pw.w = f2bf(acc[mi][ni][3]);
                    *(ushort4*)&v_out[((size_t)(bb * NH + hbase + h2) * HD + d) * SEQ + s0] = pw;
                }
        } else {
            u16* dst = (c == 0) ? q_out : k_out;
            // q gets softmax scale 1/8 plus log2(e) fold so attn can use raw v_exp_f32
            float sc = (c == 0) ? 0.125f * 1.4426950408889634f : 1.0f;
            u16* ep = smem;  // [128 rows][136] u16, chunk-XOR swizzled (overlays bufs)
            __syncthreads();  // full drain before overlay reuse
            for (int mi = 0; mi < 4; mi++)
                for (int ni = 0; ni < 4; ni++) {
                    int col = wc * 64 + ni * 16 + l15;
                    int dg = col & 63;
                    for (int r = 0; r < 4; r++) {
                        int rowl = wr * 64 + mi * 16 + lg * 4 + r;
                        int s = sbase + rowl;
                        float val = acc[mi][ni][r];
                        float part = __shfl_xor(val, 1);  // partner dim d^1 lives in lane^1
                        float2 cs = tab[(s << 5) | (dg >> 1)];
                        float o = (dg & 1) ? (val * cs.x + part * cs.y)
                                           : (val * cs.x - part * cs.y);
                        ep[rowl * 136 + (col ^ ((rowl & 7) << 3))] = f2bf(o * sc);
                    }
                }
            __syncthreads();
            // readout: 8 passes x (8 lanes per 128B s-row) -> 1KB contiguous per wave-instr
#pragma unroll
            for (int p = 0; p < 8; p++) {
                int unit = p * 32 + (tid >> 3);          // [0,256): h2*128 + s_row
                int h2 = unit >> 7, s_r = unit & 127, j = tid & 7;
                int cj = (h2 * 8 + j) ^ (s_r & 7);       // un-swizzle chunk
                uint4 w = *(const uint4*)&ep[s_r * 136 + cj * 8];
                *(uint4*)&dst[(((size_t)(bb * NH + hbase + h2) * SEQ + sbase + s_r) << 6) +
                              j * 8] = w;
            }
        }
    } else {
        for (int mi = 0; mi < 4; mi++)
            for (int ni = 0; ni < 4; ni++) {
                int col = bcol + wc * 64 + ni * 16 + l15;
                for (int r = 0; r < 4; r++) {
                    int row = brow + wr * 64 + mi * 16 + lg * 4 + r;
                    Cout[(size_t)row * Ncols + col] = acc[mi][ni][r];
                }
            }
    }
}

// ---------------- flash attention v9: attn8 + triple-buffer + counted vmcnt (T4) -----------
// Register-direct P (sigma-permuted K rows), zero bank conflicts (verified round 14).
// Same 30+2 counted-wait schedule as the GEMM.
__global__ __launch_bounds__(256, 2) void attn9_k(const u16* __restrict__ Qb,
                                                  const u16* __restrict__ Kb,
                                                  const u16* __restrict__ Vtg,
                                                  u16* __restrict__ Ob) {
    __shared__ __align__(16) u16 Ks[3][64 * 64];
    __shared__ __align__(16) u16 Vs[3][64 * 64];
    int tid = threadIdx.x, lane = tid & 63, wv = tid >> 6;
    int l15 = lane & 15, lg = lane >> 4;
    int fk = (l15 & 3) | (((l15 >> 2) & 1) << 2);  // f(sigma-row) for K reads
    int fv = (l15 & 3) | (((l15 >> 3) & 1) << 2);  // f(natural row) for V reads
    int bh = blockIdx.y, b = bh >> 4, h = bh & 15;
    int qbase = blockIdx.x * 128;
    const size_t base = (size_t)bh * SEQ * HD;  // same product for [s][d] and [d][s]

    int c0 = tid, c1 = 256 + tid;
    int r0 = c0 >> 3, s0 = ((c0 & 7) ^ ((r0 & 3) | ((r0 >> 1) & 4))) * 8;
    int r1 = c1 >> 3, s1 = ((c1 & 7) ^ ((r1 & 3) | ((r1 >> 1) & 4))) * 8;
    const u16* kp0 = Kb + base + r0 * HD + s0;
    const u16* kp1 = Kb + base + r1 * HD + s1;
    const u16* vp0 = Vtg + base + (size_t)r0 * SEQ + s0;
    const u16* vp1 = Vtg + base + (size_t)r1 * SEQ + s1;

    bf16x8 qf[2][2];
#pragma unroll
    for (int u = 0; u < 2; u++)
#pragma unroll
        for (int kt = 0; kt < 2; kt++)
            qf[u][kt] = *(const bf16x8*)&Qb[base + (size_t)(qbase + wv * 32 + u * 16 + l15) * HD +
                                            kt * 32 + lg * 8];

    f32x4 oacc[2][4];
    float Lp[2] = {0.f, 0.f};
#pragma unroll
    for (int u = 0; u < 2; u++)
#pragma unroll
        for (int nt = 0; nt < 4; nt++) oacc[u][nt] = (f32x4){0.f, 0.f, 0.f, 0.f};

    auto stage = [&](u16* Kd, u16* Vd) {  // 4 DMA/thread per tile
        GLDS16(kp0, Kd + c0 * 8);
        GLDS16(kp1, Kd + c1 * 8);
        GLDS16(vp0, Vd + c0 * 8);
        GLDS16(vp1, Vd + c1 * 8);
        kp0 += 64 * HD; kp1 += 64 * HD;
        vp0 += 64; vp1 += 64;
    };

    auto body = [&](const u16* Kl, const u16* Vl) {
        // K fragments from permuted rows sigma_nt(l15); V fragments natural
        bf16x8 kf[4][2], vf[4][2];
#pragma unroll
        for (int nt = 0; nt < 4; nt++) {
            int rk = ((nt >> 1) << 5) + ((l15 >> 2) << 3) + ((nt & 1) << 2) + (l15 & 3);
#pragma unroll
            for (int kt = 0; kt < 2; kt++) {
                kf[nt][kt] = *(const bf16x8*)&Kl[rk * 64 + (((kt * 4 + lg) ^ fk)) * 8];
                vf[nt][kt] = *(const bf16x8*)&Vl[(nt * 16 + l15) * 64 +
                                                (((kt * 4 + lg) ^ fv)) * 8];
            }
        }

        unsigned pk[2][4][2];
#pragma unroll
        for (int u = 0; u < 2; u++) {
            f32x4 sa[4];
            __builtin_amdgcn_s_setprio(1);
#pragma unroll
            for (int nt = 0; nt < 4; nt++) {
                f32x4 z = (f32x4){0.f, 0.f, 0.f, 0.f};
#pragma unroll
                for (int kt = 0; kt < 2; kt++) z = mfma16(kf[nt][kt], qf[u][kt], z);
                sa[nt] = z;
            }
            __builtin_amdgcn_s_setprio(0);
            // lane (l15,lg): sa[nt][r] = P[key=(nt>>1)*32+lg*8+(nt&1)*4+r][qrow=l15]
            float ls = 0.f;
#pragma unroll
            for (int nt = 0; nt < 4; nt++) {
                float e0 = exp2_raw(sa[nt][0]), e1 = exp2_raw(sa[nt][1]);
                float e2 = exp2_raw(sa[nt][2]), e3 = exp2_raw(sa[nt][3]);
                ls += (e0 + e1) + (e2 + e3);
                asm("v_cvt_pk_bf16_f32 %0, %1, %2" : "=v"(pk[u][nt][0]) : "v"(e0), "v"(e1));
                asm("v_cvt_pk_bf16_f32 %0, %1, %2" : "=v"(pk[u][nt][1]) : "v"(e2), "v"(e3));
            }
            Lp[u] += ls;
        }

        // PV: A-operand = P directly from registers (keys kt*32+lg*8+{0..7} per lane)
        bf16x8 pa[2][2];
#pragma unroll
        for (int u = 0; u < 2; u++)
#pragma unroll
            for (int kt = 0; kt < 2; kt++) {
                u32x4 t = {pk[u][2 * kt][0], pk[u][2 * kt][1], pk[u][2 * kt + 1][0],
                           pk[u][2 * kt + 1][1]};
                pa[u][kt] = __builtin_bit_cast(bf16x8, t);
            }
        __builtin_amdgcn_s_setprio(1);
#pragma unroll
        for (int kt = 0; kt < 2; kt++)
#pragma unroll
            for (int nt = 0; nt < 4; nt++)
#pragma unroll
                for (int u = 0; u < 2; u++)
                    oacc[u][nt] = mfma16(pa[u][kt], vf[nt][kt], oacc[u][nt]);
        __builtin_amdgcn_s_setprio(0);
    };

    // 32 tiles: prologue 2, 10 rounds of 3, tail 2 (counted vmcnt, never 0 until tail)
    stage(Ks[0], Vs[0]);
    stage(Ks[1], Vs[1]);
    for (int r = 0; r < 10; ++r) {
        GWAIT4; RBAR; stage(Ks[2], Vs[2]); body(Ks[0], Vs[0]);
        GWAIT4; RBAR; stage(Ks[0], Vs[0]); body(Ks[1], Vs[1]);
        GWAIT4; RBAR; stage(Ks[1], Vs[1]); body(Ks[2], Vs[2]);
    }
    GWAIT4; RBAR; body(Ks[0], Vs[0]);  // tile 30
    GWAIT0; RBAR; body(Ks[1], Vs[1]);  // tile 31

    float linv[2][4];
#pragma unroll
    for (int u = 0; u < 2; u++) {
        float L = Lp[u];
        L += __shfl_xor(L, 16);
        L += __shfl_xor(L, 32);
#pragma unroll
        for (int r = 0; r < 4; r++) linv[u][r] = 1.0f / __shfl(L, lg * 4 + r);
    }
#pragma unroll
    for (int u = 0; u < 2; u++)
#pragma unroll
        for (int nt = 0; nt < 4; nt++)
#pragma unroll
            for (int r = 0; r < 4; r++) {
                int row = qbase + wv * 32 + u * 16 + lg * 4 + r;
                Ob[(size_t)(b * SEQ + row) * EMB + h * HD + nt * 16 + l15] =
                    f2bf(oacc[u][nt][r] * linv[u][r]);
            }
}

// ---------------- launch ----------------

extern "C" void kernel_launch(void* const* d_in, const int* in_sizes, int n_in,
                              void* d_out, int out_size, void* d_ws, size_t ws_size,
                              hipStream_t stream) {
    const float* x = (const float*)d_in[0];
    const float* wqk = (const float*)d_in[1];
    const float* wo = (const float*)d_in[2];
    float* out = (float*)d_out;
    char* ws = (char*)d_ws;

    u16* xb = (u16*)(ws + 0);                  //  8,388,608  x as bf16 [4096][1024]
    u16* wqkvT = (u16*)(ws + 8388608);         //  6,291,456  W_qkv^T bf16 [3072][1024]
    u16* woutT = (u16*)(ws + 14680064);        //  2,097,152  W_out^T bf16 [1024][1024]
    u16* qb = (u16*)(ws + 16777216);           //  8,388,608  q roped+scaled [b][h][s][d]
    u16* kb = (u16*)(ws + 25165824);           //  8,388,608  k roped [b][h][s][d]
    u16* vb = (u16*)(ws + 33554432);           //  8,388,608  v transposed [b][h][d][s]
    u16* ao = (u16*)(ws + 41943040);           //  8,388,608  attn out [b][s][h*64+d]
    float2* tab = (float2*)(ws + 50331648);    //    524,288  cos/sin [2048][32]

    prep_k<<<5376, 256, 0, stream>>>(x, wqk, wo, xb, wqkvT, woutT, tab);
    gemm128_k<0><<<dim3(N3 / 128, MROWS / 128), 256, 0, stream>>>(xb, wqkvT, EMB, N3, qb, kb, vb,
                                                                  tab, nullptr);
    attn9_k<<<dim3(SEQ / 128, 2 * NH), 256, 0, stream>>>(qb, kb, vb, ao);
    gemm128_k<1><<<dim3(EMB / 128, MROWS / 128), 256, 0, stream>>>(ao, woutT, EMB, EMB, nullptr,
                                                                   nullptr, nullptr, nullptr, out);
}